// Round 8
// baseline (2572.903 us; speedup 1.0000x reference)
//
#include <hip/hip_runtime.h>
#include <hip/hip_bf16.h>

// MomentumDecoder: 2-layer LSTM (B=512,H=512), 256 autoregressive steps.
// Round 8: r7 structure with the flag barrier reverted to r6's proven
// agent-scope atomic protocol (r7's plain-store/sc0-poll flags hung).
//  - XCD-local groups via s_getreg(HW_REG_XCC_ID) + per-XCD rank (r6)
//  - h-state / FC partials through the XCD's L2 (plain stores + sc0/0x01 reads)
//  - gp(2) x kq(4) wave layout: each A-fragment feeds 2 gates -> A-reads /2
//  - 4-round serialized gate exchange in LDS overlapped with MFMA chunks
//  - software pipeline: PASS0(t+1) runs under the G1 exchange (bufB resident)

#define B_ 512
#define H_ 512
#define T_ 256
#define NWG 256
#define NTHR 512

typedef _Float16 half8_t __attribute__((ext_vector_type(8)));
typedef _Float16 half4_t __attribute__((ext_vector_type(4)));
typedef _Float16 half2_t __attribute__((ext_vector_type(2)));
typedef float floatx4 __attribute__((ext_vector_type(4)));

// ---- d_ws layout ----
#define W16_BYTES  (3u * 4u * H_ * H_ * 2u)     // 6 MiB f16 [W_hh0|W_ih1|W_hh1]
#define HBUF_ELEMS (B_ * H_)
#define HBUF_BYTES (HBUF_ELEMS * 2u)
#define H0_OFF   ((size_t)W16_BYTES)
#define H1_OFF   (H0_OFF + 2 * HBUF_BYTES)
#define BAR_OFF  (H1_OFF + 2 * HBUF_BYTES)      // 256 flag ints + 8 rank ints
#define PART_OFF (BAR_OFF + 2048)

__device__ __forceinline__ float sigm_(float x) { return 1.0f / (1.0f + __expf(-x)); }
__device__ __forceinline__ float tanh_(float x) { return 1.0f - 2.0f / (1.0f + __expf(2.0f * x)); }

// ---------------- prep kernels ----------------
__global__ void prep_weights(const float* __restrict__ whh0,
                             const float* __restrict__ wih1,
                             const float* __restrict__ whh1,
                             _Float16* __restrict__ w16) {
    const int QM = (4 * H_ * H_) / 4;
    int i = blockIdx.x * blockDim.x + threadIdx.x;
    if (i >= 3 * QM) return;
    const float* src; int base;
    if (i < QM)          { src = whh0; base = 0; }
    else if (i < 2 * QM) { src = wih1; base = QM; }
    else                 { src = whh1; base = 2 * QM; }
    float4 v = ((const float4*)src)[i - base];
    half4_t h;
    h[0] = (_Float16)v.x; h[1] = (_Float16)v.y; h[2] = (_Float16)v.z; h[3] = (_Float16)v.w;
    ((half4_t*)w16)[i] = h;
}

__global__ void prep_state(const float* __restrict__ h_in,
                           _Float16* __restrict__ H0, _Float16* __restrict__ H1) {
    int i = blockIdx.x * blockDim.x + threadIdx.x;
    float4 a = ((const float4*)h_in)[i];
    float4 b = ((const float4*)h_in)[(B_ * H_) / 4 + i];
    half4_t ha, hb;
    ha[0] = (_Float16)a.x; ha[1] = (_Float16)a.y; ha[2] = (_Float16)a.z; ha[3] = (_Float16)a.w;
    hb[0] = (_Float16)b.x; hb[1] = (_Float16)b.y; hb[2] = (_Float16)b.z; hb[3] = (_Float16)b.w;
    ((half4_t*)H0)[i] = ha;
    ((half4_t*)H1)[i] = hb;
}

// ---------------- helpers ----------------
// global->LDS 16B, aux=0x01 (SC0: L1 bypass; served from the XCD's L2)
#define GLL16(gp, lp) __builtin_amdgcn_global_load_lds( \
    (const __attribute__((address_space(1))) unsigned int*)(gp), \
    (__attribute__((address_space(3))) unsigned int*)(lp), 16, 0, 0x01)

__device__ __forceinline__ void stage_rows(const char* gsrc, char* lbuf, int wv, int lane) {
#pragma unroll
    for (int i = 0; i < 8; ++i) {
        int row = wv * 8 + i;
        const char* gp = gsrc + row * 1024 + (((lane ^ (row & 7)) & 63) << 4);
        GLL16(gp, lbuf + row * 1024);
    }
}

// sc0 16B load (L1 bypass, L2-served)
__device__ __forceinline__ floatx4 load16_sc0(const float* p) {
    floatx4 v;
    asm volatile("global_load_dwordx4 %0, %1, off sc0" : "=v"(v) : "v"(p) : "memory");
    return v;
}

// 4-read / 8-MFMA chunk of a pass (one mt tile, this wave's K quarter)
#define CHUNK(bufc, wfm, acc, MT) do {                                        \
    _Pragma("unroll")                                                         \
    for (int ksg = 0; ksg < 4; ++ksg) {                                       \
        int a_ = (abase + (MT) * 16384 + ksg * 64) ^ axor;                    \
        half8_t av_ = *(const half8_t*)((bufc) + a_);                         \
        _Pragma("unroll")                                                     \
        for (int g = 0; g < 2; ++g)                                           \
            acc[g][MT] = __builtin_amdgcn_mfma_f32_16x16x32_f16(              \
                av_, (wfm)[g][ksg], acc[g][MT], 0, 0, 0);                     \
    }                                                                         \
} while (0)

#define PASSFULL(bufc, wfm, acc) do {                                         \
    CHUNK(bufc, wfm, acc, 0); CHUNK(bufc, wfm, acc, 1);                       \
    CHUNK(bufc, wfm, acc, 2); CHUNK(bufc, wfm, acc, 3);                       \
} while (0)

// ---------------- main persistent kernel ----------------
__launch_bounds__(NTHR)
__global__ void lstm_decode(
    const float* __restrict__ c_in,
    const float* __restrict__ wih0, const float* __restrict__ bih0,
    const float* __restrict__ bhh0,
    const float* __restrict__ bih1, const float* __restrict__ bhh1,
    const float* __restrict__ fcw, const float* __restrict__ fcb,
    const _Float16* __restrict__ w16,
    _Float16* __restrict__ Hs0, _Float16* __restrict__ Hs1,
    int* __restrict__ bar, float* __restrict__ part,
    float* __restrict__ outp)
{
    __shared__ __align__(16) char bufA[65536];   // h1 tile
    __shared__ __align__(16) char bufB[65536];   // h0 tile (persists across phases)
    __shared__ __align__(16) float gbt[4][16][68];  // gate exchange [gate][col][row+pad]
    __shared__ __align__(16) float xrow[64];
    __shared__ int sh_bt, sh_ct;

    const int tid  = (int)threadIdx.x;
    const int lane = tid & 63;
    const int wv   = tid >> 6;    // 0..7
    const int gp   = wv & 1;      // gate pair -> gates {gp, gp+2}
    const int kq   = wv >> 1;     // K quarter (128 wide)
    const int cl   = lane & 15;
    const int kg   = lane >> 4;   // 0..3

    // ---- dynamic XCD-local group formation (r6-proven) ----
    if (tid == 0) {
        unsigned int xcc;
        asm volatile("s_getreg_b32 %0, hwreg(HW_REG_XCC_ID)" : "=s"(xcc));
        int mybt = (int)(xcc & 7u);
        int rank = atomicAdd(&bar[256 + mybt], 1);   // agent-scope
        sh_bt = mybt;
        sh_ct = rank & 31;
    }
    __syncthreads();
    const int bt = sh_bt;
    const int ct = sh_ct;

    // ---- persistent weight fragments: wfX[g][ksg], gate = gp+2*g ----
    half8_t wf0[2][4], wf1[2][4], wf2[2][4];
    float b0v[2], b1v[2], wxv[2];
#pragma unroll
    for (int g = 0; g < 2; ++g) {
        const int n = (gp + 2 * g) * H_ + ct * 16 + cl;
        const _Float16* r0 = w16 + (size_t)n * H_ + kq * 128 + kg * 8;
        const _Float16* r1 = r0 + 4 * H_ * H_;
        const _Float16* r2 = r0 + 8 * H_ * H_;
#pragma unroll
        for (int ksg = 0; ksg < 4; ++ksg) {
            wf0[g][ksg] = *(const half8_t*)(r0 + ksg * 32);
            wf1[g][ksg] = *(const half8_t*)(r1 + ksg * 32);
            wf2[g][ksg] = *(const half8_t*)(r2 + ksg * 32);
        }
        b0v[g] = bih0[n] + bhh0[n];
        b1v[g] = bih1[n] + bhh1[n];
        wxv[g] = wih0[n];
    }
    const float fcb0 = fcb[0];

    // ---- elementwise domain: thread owns (erow, ecol..ecol+1) ----
    const int erow = tid >> 3;
    const int ecol = (tid & 7) * 2;
    float c0a, c0b, c1a, c1b;
    {
        size_t base0 = (size_t)(bt * 64 + erow) * H_ + ct * 16 + ecol;
        c0a = c_in[base0];                     c0b = c_in[base0 + 1];
        c1a = c_in[(size_t)B_ * H_ + base0];   c1b = c_in[(size_t)B_ * H_ + base0 + 1];
    }
    const float2 fcv = *(const float2*)(fcw + ct * 16 + ecol);

    // A-fragment addressing: row = mt*16+cl, k = kq*128 + ksg*32 + kg*8
    const int abase = cl * 1024 + kq * 256 + kg * 16;
    const int axor  = (cl & 7) << 4;

    int* flagg   = bar + bt * 32;
    float* partg = part + bt * 2048;   // [64 rows][32 ct]
    int ep = 0;

    floatx4 accG0[2][4], accG1[2][4];

    // ---- prologue: stage h0 -> bufB, PASS0 for t=0 ----
    if (tid < 64) xrow[tid] = 0.f;
    stage_rows((const char*)Hs0 + (size_t)bt * 64 * 1024, bufB, wv, lane);
    asm volatile("s_waitcnt vmcnt(0) lgkmcnt(0)\n\ts_barrier" ::: "memory");
#pragma unroll
    for (int g = 0; g < 2; ++g)
#pragma unroll
        for (int mt = 0; mt < 4; ++mt) accG0[g][mt] = (floatx4)0.f;
    PASSFULL(bufB, wf0, accG0);        // G0(t=0) partial: h0 x W_hh0^T

    for (int t = 0; t < T_; ++t) {
        const char* h1r = (const char*)Hs1 + (size_t)(t & 1) * HBUF_BYTES + (size_t)bt * 64 * 1024;
        _Float16* h0w = Hs0 + (size_t)((t + 1) & 1) * HBUF_ELEMS;
        _Float16* h1w = Hs1 + (size_t)((t + 1) & 1) * HBUF_ELEMS;

        // ======== phase A ========
        floatx4 pv;
        if (t > 0)
            pv = load16_sc0(partg + (tid >> 3) * 32 + (tid & 7) * 4);
        stage_rows(h1r, bufA, wv, lane);          // h1 -> bufA
        if (t > 0) {
            asm volatile("s_waitcnt vmcnt(8)" : "+v"(pv) :: "memory");
            float xs = (pv[0] + pv[1]) + (pv[2] + pv[3]);
            xs += __shfl_xor(xs, 1);
            xs += __shfl_xor(xs, 2);
            xs += __shfl_xor(xs, 4);
            xs += fcb0;
            if ((tid & 7) == 0) {
                xrow[tid >> 3] = xs;
                if (ct == 0) outp[(size_t)(bt * 64 + (tid >> 3)) * T_ + (t - 1)] = xs;
            }
        }
#pragma unroll
        for (int g = 0; g < 2; ++g)
#pragma unroll
            for (int mt = 0; mt < 4; ++mt) accG1[g][mt] = (floatx4)0.f;

        // bufA staged + xrow visible across waves
        asm volatile("s_waitcnt vmcnt(0) lgkmcnt(0)\n\ts_barrier" ::: "memory");

        // ---- 4 rounds: G0 exchange (kq==j) overlapped with PASS2 chunks ----
#define ROUND_A(J)                                                            \
        if (kq == (J)) {                                                      \
            if ((J) == 0) {                                                   \
                _Pragma("unroll")                                             \
                for (int mt = 0; mt < 4; ++mt) {                              \
                    floatx4 xr = *(const floatx4*)&xrow[mt * 16 + kg * 4];    \
                    _Pragma("unroll")                                         \
                    for (int g = 0; g < 2; ++g) {                             \
                        floatx4 v = accG0[g][mt];                             \
                        _Pragma("unroll")                                     \
                        for (int r = 0; r < 4; ++r)                           \
                            v[r] = __builtin_fmaf(xr[r], wxv[g], v[r] + b0v[g]); \
                        *(floatx4*)&gbt[gp + 2 * g][cl][mt * 16 + kg * 4] = v; \
                    }                                                         \
                }                                                             \
            } else {                                                          \
                _Pragma("unroll")                                             \
                for (int g = 0; g < 2; ++g)                                   \
                _Pragma("unroll")                                             \
                for (int mt = 0; mt < 4; ++mt) {                              \
                    floatx4* p_ = (floatx4*)&gbt[gp + 2 * g][cl][mt * 16 + kg * 4]; \
                    *p_ = *p_ + accG0[g][mt];                                 \
                }                                                             \
            }                                                                 \
        }                                                                     \
        CHUNK(bufA, wf2, accG1, (J));                                         \
        __syncthreads();
        ROUND_A(0) ROUND_A(1) ROUND_A(2) ROUND_A(3)
#undef ROUND_A

        // ---- EW layer 0 ----
        {
            float ia = gbt[0][ecol][erow], ib = gbt[0][ecol + 1][erow];
            float fa = gbt[1][ecol][erow], fb = gbt[1][ecol + 1][erow];
            float ga = gbt[2][ecol][erow], gb = gbt[2][ecol + 1][erow];
            float oa = gbt[3][ecol][erow], ob = gbt[3][ecol + 1][erow];
            float ca = sigm_(fa) * c0a + sigm_(ia) * tanh_(ga);
            float cb = sigm_(fb) * c0b + sigm_(ib) * tanh_(gb);
            c0a = ca; c0b = cb;
            half2_t hh;
            hh[0] = (_Float16)(sigm_(oa) * tanh_(ca));
            hh[1] = (_Float16)(sigm_(ob) * tanh_(cb));
            *(half2_t*)(h0w + (size_t)(bt * 64 + erow) * H_ + ct * 16 + ecol) = hh;
        }
        // ---- barrier A (agent-scope atomic flags, r6-proven) ----
        ++ep;
        __syncthreads();   // drains each wave's vmcnt: h0_new stores in L2
        if (wv == 0) {
            if (lane == 0)
                __hip_atomic_store(&flagg[ct], ep, __ATOMIC_RELAXED, __HIP_MEMORY_SCOPE_AGENT);
            for (;;) {
                int v = __hip_atomic_load(&flagg[lane & 31], __ATOMIC_RELAXED, __HIP_MEMORY_SCOPE_AGENT);
                if (__all(v >= ep)) break;
            }
        }
        __syncthreads();

        // ======== phase B ========
        stage_rows((const char*)h0w + (size_t)bt * 64 * 1024, bufB, wv, lane);
        asm volatile("s_waitcnt vmcnt(0) lgkmcnt(0)\n\ts_barrier" ::: "memory");
        PASSFULL(bufB, wf1, accG1);               // G1 += h0_new x W_ih1^T

        // zero G0 for next step before pipelined PASS0 chunks
#pragma unroll
        for (int g = 0; g < 2; ++g)
#pragma unroll
            for (int mt = 0; mt < 4; ++mt) accG0[g][mt] = (floatx4)0.f;

        // ---- 4 rounds: G1 exchange overlapped with PASS0(t+1) chunks ----
#define ROUND_B(J)                                                            \
        if (kq == (J)) {                                                      \
            if ((J) == 0) {                                                   \
                _Pragma("unroll")                                             \
                for (int g = 0; g < 2; ++g)                                   \
                _Pragma("unroll")                                             \
                for (int mt = 0; mt < 4; ++mt) {                              \
                    floatx4 v = accG1[g][mt] + b1v[g];                        \
                    *(floatx4*)&gbt[gp + 2 * g][cl][mt * 16 + kg * 4] = v;    \
                }                                                             \
            } else {                                                          \
                _Pragma("unroll")                                             \
                for (int g = 0; g < 2; ++g)                                   \
                _Pragma("unroll")                                             \
                for (int mt = 0; mt < 4; ++mt) {                              \
                    floatx4* p_ = (floatx4*)&gbt[gp + 2 * g][cl][mt * 16 + kg * 4]; \
                    *p_ = *p_ + accG1[g][mt];                                 \
                }                                                             \
            }                                                                 \
        }                                                                     \
        CHUNK(bufB, wf0, accG0, (J));                                         \
        __syncthreads();
        ROUND_B(0) ROUND_B(1) ROUND_B(2) ROUND_B(3)
#undef ROUND_B

        // ---- EW layer 1 + FC partial ----
        {
            float ia = gbt[0][ecol][erow], ib = gbt[0][ecol + 1][erow];
            float fa = gbt[1][ecol][erow], fb = gbt[1][ecol + 1][erow];
            float ga = gbt[2][ecol][erow], gb = gbt[2][ecol + 1][erow];
            float oa = gbt[3][ecol][erow], ob = gbt[3][ecol + 1][erow];
            float ca = sigm_(fa) * c1a + sigm_(ia) * tanh_(ga);
            float cb = sigm_(fb) * c1b + sigm_(ib) * tanh_(gb);
            c1a = ca; c1b = cb;
            float ha = sigm_(oa) * tanh_(ca);
            float hb = sigm_(ob) * tanh_(cb);
            half2_t hh; hh[0] = (_Float16)ha; hh[1] = (_Float16)hb;
            *(half2_t*)(h1w + (size_t)(bt * 64 + erow) * H_ + ct * 16 + ecol) = hh;
            float ps = __builtin_fmaf(ha, fcv.x, hb * fcv.y);
            ps += __shfl_xor(ps, 1);
            ps += __shfl_xor(ps, 2);
            ps += __shfl_xor(ps, 4);
            if ((tid & 7) == 0)
                partg[erow * 32 + ct] = ps;
        }
        // ---- barrier B ----
        ++ep;
        __syncthreads();
        if (wv == 0) {
            if (lane == 0)
                __hip_atomic_store(&flagg[ct], ep, __ATOMIC_RELAXED, __HIP_MEMORY_SCOPE_AGENT);
            for (;;) {
                int v = __hip_atomic_load(&flagg[lane & 31], __ATOMIC_RELAXED, __HIP_MEMORY_SCOPE_AGENT);
                if (__all(v >= ep)) break;
            }
        }
        __syncthreads();
    }

    // epilogue: final x -> outp column T_-1
    if (ct == 0) {
        floatx4 pv = load16_sc0(partg + (tid >> 3) * 32 + (tid & 7) * 4);
        asm volatile("s_waitcnt vmcnt(0)" : "+v"(pv) :: "memory");
        float xs = (pv[0] + pv[1]) + (pv[2] + pv[3]);
        xs += __shfl_xor(xs, 1);
        xs += __shfl_xor(xs, 2);
        xs += __shfl_xor(xs, 4);
        xs += fcb0;
        if ((tid & 7) == 0)
            outp[(size_t)(bt * 64 + (tid >> 3)) * T_ + (T_ - 1)] = xs;
    }
}

extern "C" void kernel_launch(void* const* d_in, const int* in_sizes, int n_in,
                              void* d_out, int out_size, void* d_ws, size_t ws_size,
                              hipStream_t stream) {
    const float* h_in = (const float*)d_in[0];
    const float* c_in = (const float*)d_in[1];
    const float* wih0 = (const float*)d_in[2];
    const float* whh0 = (const float*)d_in[3];
    const float* bih0 = (const float*)d_in[4];
    const float* bhh0 = (const float*)d_in[5];
    const float* wih1 = (const float*)d_in[6];
    const float* whh1 = (const float*)d_in[7];
    const float* bih1 = (const float*)d_in[8];
    const float* bhh1 = (const float*)d_in[9];
    const float* fcw  = (const float*)d_in[10];
    const float* fcb  = (const float*)d_in[11];
    float* out = (float*)d_out;

    char* ws = (char*)d_ws;
    _Float16* w16 = (_Float16*)ws;
    _Float16* Hs0 = (_Float16*)(ws + H0_OFF);
    _Float16* Hs1 = (_Float16*)(ws + H1_OFF);
    int* bar      = (int*)(ws + BAR_OFF);
    float* part   = (float*)(ws + PART_OFF);

    // flags + rank counters must start at 0 (ws poisoned between calls)
    (void)hipMemsetAsync(bar, 0, 2048, stream);

    {
        const int n4 = 3 * (4 * H_ * H_) / 4;
        prep_weights<<<(n4 + 255) / 256, 256, 0, stream>>>(whh0, wih1, whh1, w16);
    }
    prep_state<<<(B_ * H_ / 4) / 256, 256, 0, stream>>>(h_in, Hs0, Hs1);

    lstm_decode<<<NWG, NTHR, 0, stream>>>(c_in, wih0, bih0, bhh0, bih1, bhh1,
                                          fcw, fcb, w16, Hs0, Hs1, bar, part, out);
}

// Round 9
// 2364.233 us; speedup vs baseline: 1.0883x; 1.0883x over previous
//
#include <hip/hip_runtime.h>
#include <hip/hip_bf16.h>

// MomentumDecoder: 2-layer LSTM (B=512,H=512), 256 autoregressive steps.
// Round 9: dual-tile pipelined WG. 256 WGs x 512 thr (1/CU). Each XCD owns 2
// batch tiles (32 rows each); its 32 WGs interleave the two independent
// recurrences offset by half a step, so every cross-WG barrier's latency is
// hidden under the other tile's compute slot:
//   C1=alphaA(t) -> C2=betaB(t-1) -> C3=alphaB(t) -> C4=betaA(t)
// Weights stay in VGPRs (96/lane, shared by both tiles). Gate reduce = 2-round
// pairwise LDS tree. Flags = r6-proven agent-scope atomics. Data path = XCD L2.

#define B_ 512
#define H_ 512
#define T_ 256
#define NWG 256
#define NTHR 512

typedef _Float16 half8_t __attribute__((ext_vector_type(8)));
typedef _Float16 half4_t __attribute__((ext_vector_type(4)));
typedef float floatx4 __attribute__((ext_vector_type(4)));
typedef float floatx2 __attribute__((ext_vector_type(2)));

// ---- d_ws layout ----
#define W16_BYTES  (3u * 4u * H_ * H_ * 2u)     // 6 MiB f16 [W_hh0|W_ih1|W_hh1]
#define HBUF_ELEMS (B_ * H_)
#define HBUF_BYTES (HBUF_ELEMS * 2u)
#define H0_OFF   ((size_t)W16_BYTES)
#define H1_OFF   (H0_OFF + 2 * HBUF_BYTES)
#define BAR_OFF  (H1_OFF + 2 * HBUF_BYTES)      // flagsA[512] flagsB[512] rank[8]
#define PART_OFF (BAR_OFF + 8192)               // 16 tiles x 32 rows x 32 ct f32

__device__ __forceinline__ float sigm_(float x) { return 1.0f / (1.0f + __expf(-x)); }
__device__ __forceinline__ float tanh_(float x) { return 1.0f - 2.0f / (1.0f + __expf(2.0f * x)); }

// ---------------- prep kernels ----------------
__global__ void prep_weights(const float* __restrict__ whh0,
                             const float* __restrict__ wih1,
                             const float* __restrict__ whh1,
                             _Float16* __restrict__ w16) {
    const int QM = (4 * H_ * H_) / 4;
    int i = blockIdx.x * blockDim.x + threadIdx.x;
    if (i >= 3 * QM) return;
    const float* src; int base;
    if (i < QM)          { src = whh0; base = 0; }
    else if (i < 2 * QM) { src = wih1; base = QM; }
    else                 { src = whh1; base = 2 * QM; }
    float4 v = ((const float4*)src)[i - base];
    half4_t h;
    h[0] = (_Float16)v.x; h[1] = (_Float16)v.y; h[2] = (_Float16)v.z; h[3] = (_Float16)v.w;
    ((half4_t*)w16)[i] = h;
}

__global__ void prep_state(const float* __restrict__ h_in,
                           _Float16* __restrict__ H0, _Float16* __restrict__ H1) {
    int i = blockIdx.x * blockDim.x + threadIdx.x;
    float4 a = ((const float4*)h_in)[i];
    float4 b = ((const float4*)h_in)[(B_ * H_) / 4 + i];
    half4_t ha, hb;
    ha[0] = (_Float16)a.x; ha[1] = (_Float16)a.y; ha[2] = (_Float16)a.z; ha[3] = (_Float16)a.w;
    hb[0] = (_Float16)b.x; hb[1] = (_Float16)b.y; hb[2] = (_Float16)b.z; hb[3] = (_Float16)b.w;
    ((half4_t*)H0)[i] = ha;
    ((half4_t*)H1)[i] = hb;
}

// ---------------- helpers ----------------
// global->LDS 16B, aux=0x01 (SC0: L1 bypass; served from the XCD's L2)
#define GLL16(gptr, lptr) __builtin_amdgcn_global_load_lds( \
    (const __attribute__((address_space(1))) unsigned int*)(gptr), \
    (__attribute__((address_space(3))) unsigned int*)(lptr), 16, 0, 0x01)

// Stage this wave's 4 rows of a 32x512 f16 tile (pre-swizzled source).
__device__ __forceinline__ void stage32(const char* gsrc, char* lbuf, int wv, int lane) {
#pragma unroll
    for (int i = 0; i < 4; ++i) {
        int row = wv * 4 + i;
        const char* g_ = gsrc + row * 1024 + (((lane ^ (row & 7)) & 63) << 4);
        GLL16(g_, lbuf + row * 1024);
    }
}

__device__ __forceinline__ floatx2 load8_sc0(const float* p) {
    floatx2 v;
    asm volatile("global_load_dwordx2 %0, %1, off sc0" : "=v"(v) : "v"(p) : "memory");
    return v;
}

// ---------------- main persistent kernel ----------------
__launch_bounds__(NTHR)
__global__ void lstm_decode(
    const float* __restrict__ c_in,
    const float* __restrict__ wih0, const float* __restrict__ bih0,
    const float* __restrict__ bhh0,
    const float* __restrict__ bih1, const float* __restrict__ bhh1,
    const float* __restrict__ fcw, const float* __restrict__ fcb,
    const _Float16* __restrict__ w16,
    _Float16* __restrict__ Hs0, _Float16* __restrict__ Hs1,
    int* __restrict__ bar, float* __restrict__ part,
    float* __restrict__ outp)
{
    __shared__ __align__(16) char bufA[32768];    // shared h1 staging (C1/C4)
    __shared__ __align__(16) char bufBa[32768];   // tile-alpha h0
    __shared__ __align__(16) char bufBb[32768];   // tile-beta h0
    __shared__ __align__(16) float gb2a[4][2][16][36];
    __shared__ __align__(16) float gb2b[4][2][16][36];
    __shared__ float xrowa[32], xrowb[32];
    __shared__ int sh_ta, sh_ct;

    const int tid  = (int)threadIdx.x;
    const int lane = tid & 63;
    const int wv   = tid >> 6;    // 0..7
    const int gp_  = wv & 1;      // gate pair -> gates {gp_, gp_+2}
    const int kq   = wv >> 1;     // K quarter (128 wide)
    const int cl   = lane & 15;
    const int kg   = lane >> 4;   // 0..3
    const int erow = tid >> 4;    // 0..31 elementwise row
    const int ecol = tid & 15;    // 0..15 elementwise col

    // ---- XCD-local group formation (r6-proven) ----
    if (tid == 0) {
        unsigned int xcc;
        asm volatile("s_getreg_b32 %0, hwreg(HW_REG_XCC_ID)" : "=s"(xcc));
        int rank = atomicAdd(&bar[1024 + (int)(xcc & 7u)], 1);
        sh_ta = (int)(xcc & 7u) * 2;
        sh_ct = rank & 31;
    }
    __syncthreads();
    const int ta = sh_ta;        // tile alpha (rows ta*32..)
    const int tb = sh_ta + 1;    // tile beta
    const int ct = sh_ct;

    // ---- persistent weight fragments: wfX[g][ksg], gate = gp_+2*g ----
    half8_t wf0[2][4], wf1[2][4], wf2[2][4];
    float b0v[2], b1v[2], wxv[2];
#pragma unroll
    for (int g = 0; g < 2; ++g) {
        const int n = (gp_ + 2 * g) * H_ + ct * 16 + cl;
        const _Float16* r0 = w16 + (size_t)n * H_ + kq * 128 + kg * 8;
        const _Float16* r1 = r0 + 4 * H_ * H_;
        const _Float16* r2 = r0 + 8 * H_ * H_;
#pragma unroll
        for (int ksg = 0; ksg < 4; ++ksg) {
            wf0[g][ksg] = *(const half8_t*)(r0 + ksg * 32);
            wf1[g][ksg] = *(const half8_t*)(r1 + ksg * 32);
            wf2[g][ksg] = *(const half8_t*)(r2 + ksg * 32);
        }
        b0v[g] = bih0[n] + bhh0[n];
        b1v[g] = bih1[n] + bhh1[n];
        wxv[g] = wih0[n];
    }
    const float fcb0 = fcb[0];
    const float fcv  = fcw[ct * 16 + ecol];

    // ---- c-state: 1 elem/thread per layer per tile ----
    float c0a_, c1a_, c0b_, c1b_;
    {
        size_t ba = (size_t)(ta * 32 + erow) * H_ + ct * 16 + ecol;
        size_t bb = (size_t)(tb * 32 + erow) * H_ + ct * 16 + ecol;
        c0a_ = c_in[ba];                    c1a_ = c_in[(size_t)B_ * H_ + ba];
        c0b_ = c_in[bb];                    c1b_ = c_in[(size_t)B_ * H_ + bb];
    }

    const int abase = cl * 1024 + kq * 256 + kg * 16;
    const int axor  = (cl & 7) << 4;

    int* flA_a = bar + ta * 32;
    int* flB_a = bar + 512 + ta * 32;
    int* flA_b = bar + tb * 32;
    int* flB_b = bar + 512 + tb * 32;
    float* pga = part + ta * 1024;   // [32 rows][32 ct]
    float* pgb = part + tb * 1024;

    floatx4 g0a[2][2], g1a[2][2], g0b[2][2], g1b[2][2];

#define PASSX(bufc, wfm, ACC) do {                                            \
    _Pragma("unroll")                                                         \
    for (int mt = 0; mt < 2; ++mt)                                            \
    _Pragma("unroll")                                                         \
    for (int ksg = 0; ksg < 4; ++ksg) {                                       \
        int a_ = (abase + mt * 16384 + ksg * 64) ^ axor;                      \
        half8_t av_ = *(const half8_t*)((bufc) + a_);                         \
        _Pragma("unroll")                                                     \
        for (int g = 0; g < 2; ++g)                                           \
            ACC[g][mt] = __builtin_amdgcn_mfma_f32_16x16x32_f16(              \
                av_, (wfm)[g][ksg], ACC[g][mt], 0, 0, 0);                     \
    }                                                                         \
} while (0)

#define ZEROA(ACC) do {                                                       \
    _Pragma("unroll")                                                         \
    for (int g = 0; g < 2; ++g)                                               \
    _Pragma("unroll")                                                         \
    for (int mt = 0; mt < 2; ++mt) ACC[g][mt] = (floatx4)0.f;                 \
} while (0)

#define POLLW(FL, TGT) do {                                                   \
    if (wv == 0) {                                                            \
        for (;;) {                                                            \
            int v_ = __hip_atomic_load(&(FL)[lane & 31], __ATOMIC_RELAXED,    \
                                       __HIP_MEMORY_SCOPE_AGENT);             \
            if (__all(v_ >= (TGT))) break;                                    \
        }                                                                     \
    }                                                                         \
    __syncthreads();                                                          \
} while (0)

#define SIGNAL(FL, VAL) do {                                                  \
    __syncthreads();                                                          \
    if (tid == 0)                                                             \
        __hip_atomic_store(&(FL)[ct], (VAL), __ATOMIC_RELAXED,                \
                           __HIP_MEMORY_SCOPE_AGENT);                         \
} while (0)

// 2-round pairwise kq-tree: odd kq write, even kq add (kq0 injects extras)
#define XCHG_ST(GB, ACC) do {                                                 \
    if (kq & 1) {                                                             \
        _Pragma("unroll")                                                     \
        for (int g = 0; g < 2; ++g)                                           \
        _Pragma("unroll")                                                     \
        for (int mt = 0; mt < 2; ++mt)                                        \
            *(floatx4*)&GB[gp_ + 2 * g][kq >> 1][cl][mt * 16 + kg * 4] = ACC[g][mt]; \
    }                                                                         \
    __syncthreads();                                                          \
} while (0)

#define XCHG_G0(GB, ACC, XROW) do {                                           \
    if (!(kq & 1)) {                                                          \
        _Pragma("unroll")                                                     \
        for (int g = 0; g < 2; ++g)                                           \
        _Pragma("unroll")                                                     \
        for (int mt = 0; mt < 2; ++mt) {                                      \
            floatx4 v_ = ACC[g][mt];                                          \
            if (kq == 0) {                                                    \
                _Pragma("unroll")                                             \
                for (int r = 0; r < 4; ++r)                                   \
                    v_[r] += __builtin_fmaf(XROW[mt * 16 + kg * 4 + r], wxv[g], b0v[g]); \
            }                                                                 \
            floatx4* p_ = (floatx4*)&GB[gp_ + 2 * g][kq >> 1][cl][mt * 16 + kg * 4]; \
            *p_ = *p_ + v_;                                                   \
        }                                                                     \
    }                                                                         \
    __syncthreads();                                                          \
} while (0)

#define XCHG_G1(GB, ACC) do {                                                 \
    if (!(kq & 1)) {                                                          \
        _Pragma("unroll")                                                     \
        for (int g = 0; g < 2; ++g)                                           \
        _Pragma("unroll")                                                     \
        for (int mt = 0; mt < 2; ++mt) {                                      \
            floatx4 v_ = ACC[g][mt];                                          \
            if (kq == 0) {                                                    \
                _Pragma("unroll")                                             \
                for (int r = 0; r < 4; ++r) v_[r] += b1v[g];                  \
            }                                                                 \
            floatx4* p_ = (floatx4*)&GB[gp_ + 2 * g][kq >> 1][cl][mt * 16 + kg * 4]; \
            *p_ = *p_ + v_;                                                   \
        }                                                                     \
    }                                                                         \
    __syncthreads();                                                          \
} while (0)

#define EW0(GB, C0, HWP, TROW) do {                                           \
    float i_ = GB[0][0][ecol][erow] + GB[0][1][ecol][erow];                   \
    float f_ = GB[1][0][ecol][erow] + GB[1][1][ecol][erow];                   \
    float q_ = GB[2][0][ecol][erow] + GB[2][1][ecol][erow];                   \
    float o_ = GB[3][0][ecol][erow] + GB[3][1][ecol][erow];                   \
    float cc = sigm_(f_) * (C0) + sigm_(i_) * tanh_(q_);                      \
    (C0) = cc;                                                                \
    float hv = sigm_(o_) * tanh_(cc);                                         \
    *((HWP) + (size_t)((TROW) + erow) * H_ + ct * 16 + ecol) = (_Float16)hv;  \
} while (0)

#define EW1(GB, C1, HWP, TROW, PG) do {                                       \
    float i_ = GB[0][0][ecol][erow] + GB[0][1][ecol][erow];                   \
    float f_ = GB[1][0][ecol][erow] + GB[1][1][ecol][erow];                   \
    float q_ = GB[2][0][ecol][erow] + GB[2][1][ecol][erow];                   \
    float o_ = GB[3][0][ecol][erow] + GB[3][1][ecol][erow];                   \
    float cc = sigm_(f_) * (C1) + sigm_(i_) * tanh_(q_);                      \
    (C1) = cc;                                                                \
    float hv = sigm_(o_) * tanh_(cc);                                         \
    *((HWP) + (size_t)((TROW) + erow) * H_ + ct * 16 + ecol) = (_Float16)hv;  \
    float ps = hv * fcv;                                                      \
    ps += __shfl_xor(ps, 1); ps += __shfl_xor(ps, 2);                         \
    ps += __shfl_xor(ps, 4); ps += __shfl_xor(ps, 8);                         \
    if ((tid & 15) == 0) (PG)[erow * 32 + ct] = ps;                           \
} while (0)

    // ---- prologue ----
    if (tid < 32) { xrowa[tid] = 0.f; xrowb[tid] = 0.f; }
    stage32((const char*)Hs0 + (size_t)ta * 32 * 1024, bufBa, wv, lane);
    stage32((const char*)Hs0 + (size_t)tb * 32 * 1024, bufBb, wv, lane);
    asm volatile("s_waitcnt vmcnt(0) lgkmcnt(0)\n\ts_barrier" ::: "memory");
    ZEROA(g0a); ZEROA(g0b);
    PASSX(bufBa, wf0, g0a);            // G0-alpha(t=0) partial
    PASSX(bufBb, wf0, g0b);            // G0-beta(t=0) partial

    for (int t = 0; t < T_; ++t) {
        const size_t pcur = (size_t)(t & 1);
        const size_t pnxt = (size_t)((t + 1) & 1);

        // ======== C1: alpha phase A, step t ========
        POLLW(flB_a, t);
        floatx2 pva;
        if (t > 0) pva = load8_sc0(pga + erow * 32 + (tid & 15) * 2);
        stage32((const char*)Hs1 + pcur * HBUF_BYTES + (size_t)ta * 32 * 1024, bufA, wv, lane);
        if (t > 0) {
            asm volatile("s_waitcnt vmcnt(4)" : "+v"(pva) :: "memory");
            float xs = pva[0] + pva[1];
            xs += __shfl_xor(xs, 1); xs += __shfl_xor(xs, 2);
            xs += __shfl_xor(xs, 4); xs += __shfl_xor(xs, 8);
            xs += fcb0;
            if ((tid & 15) == 0) {
                xrowa[erow] = xs;
                if (ct == 0) outp[(size_t)(ta * 32 + erow) * T_ + (t - 1)] = xs;
            }
        }
        ZEROA(g1a);
        asm volatile("s_waitcnt vmcnt(0) lgkmcnt(0)\n\ts_barrier" ::: "memory");
        PASSX(bufA, wf2, g1a);                       // h1a x W_hh1^T
        XCHG_ST(gb2a, g0a);
        XCHG_G0(gb2a, g0a, xrowa);
        EW0(gb2a, c0a_, Hs0 + pnxt * HBUF_ELEMS, ta * 32);
        SIGNAL(flA_a, t + 1);

        // ======== C2: beta phase B, step t-1 ========
        if (t > 0) {
            POLLW(flA_b, t);
            stage32((const char*)Hs0 + pcur * HBUF_BYTES + (size_t)tb * 32 * 1024, bufBb, wv, lane);
            asm volatile("s_waitcnt vmcnt(0) lgkmcnt(0)\n\ts_barrier" ::: "memory");
            PASSX(bufBb, wf1, g1b);                  // h0b_new x W_ih1^T
            XCHG_ST(gb2b, g1b);
            XCHG_G1(gb2b, g1b);
            EW1(gb2b, c1b_, Hs1 + pcur * HBUF_ELEMS, tb * 32, pgb);
            ZEROA(g0b);
            PASSX(bufBb, wf0, g0b);                  // pipelined G0-beta(t)
            SIGNAL(flB_b, t);
        }

        // ======== C3: alpha phase B, step t ========
        POLLW(flA_a, t + 1);
        stage32((const char*)Hs0 + pnxt * HBUF_BYTES + (size_t)ta * 32 * 1024, bufBa, wv, lane);
        asm volatile("s_waitcnt vmcnt(0) lgkmcnt(0)\n\ts_barrier" ::: "memory");
        PASSX(bufBa, wf1, g1a);                      // h0a_new x W_ih1^T
        XCHG_ST(gb2a, g1a);
        XCHG_G1(gb2a, g1a);
        EW1(gb2a, c1a_, Hs1 + pnxt * HBUF_ELEMS, ta * 32, pga);
        ZEROA(g0a);
        PASSX(bufBa, wf0, g0a);                      // pipelined G0-alpha(t+1)
        SIGNAL(flB_a, t + 1);

        // ======== C4: beta phase A, step t ========
        POLLW(flB_b, t);
        floatx2 pvb;
        if (t > 0) pvb = load8_sc0(pgb + erow * 32 + (tid & 15) * 2);
        stage32((const char*)Hs1 + pcur * HBUF_BYTES + (size_t)tb * 32 * 1024, bufA, wv, lane);
        if (t > 0) {
            asm volatile("s_waitcnt vmcnt(4)" : "+v"(pvb) :: "memory");
            float xs = pvb[0] + pvb[1];
            xs += __shfl_xor(xs, 1); xs += __shfl_xor(xs, 2);
            xs += __shfl_xor(xs, 4); xs += __shfl_xor(xs, 8);
            xs += fcb0;
            if ((tid & 15) == 0) {
                xrowb[erow] = xs;
                if (ct == 0) outp[(size_t)(tb * 32 + erow) * T_ + (t - 1)] = xs;
            }
        }
        ZEROA(g1b);
        asm volatile("s_waitcnt vmcnt(0) lgkmcnt(0)\n\ts_barrier" ::: "memory");
        PASSX(bufA, wf2, g1b);                       // h1b x W_hh1^T
        XCHG_ST(gb2b, g0b);
        XCHG_G0(gb2b, g0b, xrowb);
        EW0(gb2b, c0b_, Hs0 + pnxt * HBUF_ELEMS, tb * 32);
        SIGNAL(flA_b, t + 1);
    }

    // ======== epilogue: beta phase B, step 255 ========
    {
        POLLW(flA_b, T_);
        stage32((const char*)Hs0 + 0 * HBUF_BYTES + (size_t)tb * 32 * 1024, bufBb, wv, lane);
        asm volatile("s_waitcnt vmcnt(0) lgkmcnt(0)\n\ts_barrier" ::: "memory");
        PASSX(bufBb, wf1, g1b);
        XCHG_ST(gb2b, g1b);
        XCHG_G1(gb2b, g1b);
        EW1(gb2b, c1b_, Hs1 + 0 * HBUF_ELEMS, tb * 32, pgb);
        SIGNAL(flB_b, T_);
    }
    // final x for alpha (col 255)
    if (ct == 0) {
        POLLW(flB_a, T_);
        floatx2 pv = load8_sc0(pga + erow * 32 + (tid & 15) * 2);
        asm volatile("s_waitcnt vmcnt(0)" : "+v"(pv) :: "memory");
        float xs = pv[0] + pv[1];
        xs += __shfl_xor(xs, 1); xs += __shfl_xor(xs, 2);
        xs += __shfl_xor(xs, 4); xs += __shfl_xor(xs, 8);
        xs += fcb0;
        if ((tid & 15) == 0) outp[(size_t)(ta * 32 + erow) * T_ + (T_ - 1)] = xs;
    }
    // final x for beta (col 255)
    if (ct == 0) {
        POLLW(flB_b, T_);
        floatx2 pv = load8_sc0(pgb + erow * 32 + (tid & 15) * 2);
        asm volatile("s_waitcnt vmcnt(0)" : "+v"(pv) :: "memory");
        float xs = pv[0] + pv[1];
        xs += __shfl_xor(xs, 1); xs += __shfl_xor(xs, 2);
        xs += __shfl_xor(xs, 4); xs += __shfl_xor(xs, 8);
        xs += fcb0;
        if ((tid & 15) == 0) outp[(size_t)(tb * 32 + erow) * T_ + (T_ - 1)] = xs;
    }
}

extern "C" void kernel_launch(void* const* d_in, const int* in_sizes, int n_in,
                              void* d_out, int out_size, void* d_ws, size_t ws_size,
                              hipStream_t stream) {
    const float* h_in = (const float*)d_in[0];
    const float* c_in = (const float*)d_in[1];
    const float* wih0 = (const float*)d_in[2];
    const float* whh0 = (const float*)d_in[3];
    const float* bih0 = (const float*)d_in[4];
    const float* bhh0 = (const float*)d_in[5];
    const float* wih1 = (const float*)d_in[6];
    const float* whh1 = (const float*)d_in[7];
    const float* bih1 = (const float*)d_in[8];
    const float* bhh1 = (const float*)d_in[9];
    const float* fcw  = (const float*)d_in[10];
    const float* fcb  = (const float*)d_in[11];
    float* out = (float*)d_out;

    char* ws = (char*)d_ws;
    _Float16* w16 = (_Float16*)ws;
    _Float16* Hs0 = (_Float16*)(ws + H0_OFF);
    _Float16* Hs1 = (_Float16*)(ws + H1_OFF);
    int* bar      = (int*)(ws + BAR_OFF);
    float* part   = (float*)(ws + PART_OFF);

    // flags + rank counters must start at 0 (ws poisoned between calls)
    (void)hipMemsetAsync(bar, 0, 8192, stream);

    {
        const int n4 = 3 * (4 * H_ * H_) / 4;
        prep_weights<<<(n4 + 255) / 256, 256, 0, stream>>>(whh0, wih1, whh1, w16);
    }
    prep_state<<<(B_ * H_ / 4) / 256, 256, 0, stream>>>(h_in, Hs0, Hs1);

    lstm_decode<<<NWG, NTHR, 0, stream>>>(c_in, wih0, bih0, bhh0, bih1, bhh1,
                                          fcw, fcb, w16, Hs0, Hs1, bar, part, out);
}